// Round 7
// baseline (180.099 us; speedup 1.0000x reference)
//
#include <hip/hip_runtime.h>

// Problem dims (ViT-Base LoRA-MoE qkv)
#define TOK 8192      // B*S = 32*256
#define DD  768       // in features
#define NOUT 2304     // 3*D
#define TT  8         // saved tasks
#define RR  16        // LoRA rank
#define KRANK 144     // T*R + R (per branch folded rank)

typedef __bf16 bf16;
typedef __bf16 bf16x4 __attribute__((ext_vector_type(4)));
typedef __bf16 bf16x8 __attribute__((ext_vector_type(8)));
typedef float  floatx4 __attribute__((ext_vector_type(4)));

__device__ __forceinline__ void gl_lds16(const void* g, void* l) {
    __builtin_amdgcn_global_load_lds((const __attribute__((address_space(1))) void*)g,
                                     (__attribute__((address_space(3))) void*)l, 16, 0, 0);
}

// ----------------------------------------------------------------- prep ----
// R13: norms ONLY (32 blocks). The x fp32->bf16 cast pass is gone — the cast
// is fused into gemm's A-staging (x f32 panels are L2-resident there: 3MB
// per-XCD slice < 4MB L2). Saves 25MB read + 12.6MB write + 12.6MB re-read
// of HBM traffic and a 3104-block dispatch.
__global__ __launch_bounds__(256) void prep_kernel(
    const float* __restrict__ A_q, const float* __restrict__ B_q,
    const float* __restrict__ A_v, const float* __restrict__ B_v,
    float* __restrict__ norms)
{
    __shared__ float ws4[4];
    const int b = blockIdx.x;
    const float* base;
    switch (b >> 3) {
        case 0: base = A_q; break;
        case 1: base = B_q; break;
        case 2: base = A_v; break;
        default: base = B_v; break;
    }
    base += (b & 7) * (RR * DD);
    float s = 0.f;
    for (int i = threadIdx.x; i < RR * DD; i += 256) {
        float v = base[i];
        s = fmaf(v, v, s);
    }
    #pragma unroll
    for (int off = 32; off > 0; off >>= 1) s += __shfl_down(s, off);
    if ((threadIdx.x & 63) == 0) ws4[threadIdx.x >> 6] = s;
    __syncthreads();
    if (threadIdx.x == 0)
        norms[b] = sqrtf(ws4[0] + ws4[1] + ws4[2] + ws4[3]);
}

// ----------------------------------------------------------------- fold ----
// Wc[row] = bf16(qkv_w[row] + sum_i c[row][i] * Acat[i][:]) for q/v thirds;
// plain bf16 cast for the k third. grid = (3, 288).  (unchanged, verified)
__global__ __launch_bounds__(256) void fold_kernel(
    const float* __restrict__ qkv_w,
    const float* __restrict__ A_q, const float* __restrict__ la_q,
    const float* __restrict__ B_q, const float* __restrict__ lb_q,
    const float* __restrict__ A_v, const float* __restrict__ la_v,
    const float* __restrict__ B_v, const float* __restrict__ lb_v,
    const float* __restrict__ gate_logits, const float* __restrict__ alpha,
    const float* __restrict__ norms, bf16* __restrict__ Wc)
{
    const int tid = threadIdx.x;
    const int d = blockIdx.x * 256 + tid;
    const int gy = blockIdx.y;

    if (gy >= 96 && gy < 192) {           // k third: pure cast
        const int rowbase = DD + (gy - 96) * 8;
        #pragma unroll
        for (int j = 0; j < 8; ++j) {
            const int row = rowbase + j;
            Wc[row * DD + d] = (bf16)qkv_w[row * DD + d];
        }
        return;
    }

    __shared__ float c_lds[8 * KRANK];
    __shared__ float sc_sh[TT];
    __shared__ float acur_sh;

    const bool is_v = (gy >= 192);
    const int e0 = (is_v ? gy - 192 : gy) * 8;
    const float* Astack = is_v ? A_v : A_q;
    const float* la     = is_v ? la_v : la_q;
    const float* Bmat   = is_v ? B_v : B_q;
    const float* lb     = is_v ? lb_v : lb_q;
    const float* nA     = norms + (is_v ? 16 : 0);
    const float* nB     = norms + (is_v ? 24 : 8);
    const int rowbase   = (is_v ? 2 * DD : 0) + e0;

    if (tid == 0) {
        float mx = gate_logits[0];
        for (int t = 1; t < TT; ++t) mx = fmaxf(mx, gate_logits[t]);
        float e[TT], s = 0.f;
        for (int t = 0; t < TT; ++t) { e[t] = __expf(gate_logits[t] - mx); s += e[t]; }
        for (int t = 0; t < TT; ++t) sc_sh[t] = (e[t] / s) / (nA[t] * nB[t]);
        acur_sh = alpha[TT];
    }
    __syncthreads();

    for (int idx = tid; idx < 8 * KRANK; idx += 256) {
        const int j = idx / KRANK, i = idx - j * KRANK;
        const int e = e0 + j;
        float v;
        if (i < TT * RR) {
            const int t = i >> 4, r = i & 15;
            v = sc_sh[t] * Bmat[(t * DD + e) * RR + r];
        } else {
            v = acur_sh * lb[e * RR + (i - TT * RR)];
        }
        c_lds[j * KRANK + i] = v;
    }
    __syncthreads();

    float acc[8] = {0.f, 0.f, 0.f, 0.f, 0.f, 0.f, 0.f, 0.f};

    for (int i = 0; i < TT * RR; i += 4) {
        const float a0 = Astack[(i + 0) * DD + d];
        const float a1 = Astack[(i + 1) * DD + d];
        const float a2 = Astack[(i + 2) * DD + d];
        const float a3 = Astack[(i + 3) * DD + d];
        #pragma unroll
        for (int j = 0; j < 8; ++j) {
            const float4 cv = *(const float4*)&c_lds[j * KRANK + i];
            acc[j] = fmaf(a0, cv.x, fmaf(a1, cv.y, fmaf(a2, cv.z, fmaf(a3, cv.w, acc[j]))));
        }
    }
    #pragma unroll
    for (int i = 0; i < RR; i += 4) {
        const float a0 = la[(i + 0) * DD + d];
        const float a1 = la[(i + 1) * DD + d];
        const float a2 = la[(i + 2) * DD + d];
        const float a3 = la[(i + 3) * DD + d];
        #pragma unroll
        for (int j = 0; j < 8; ++j) {
            const float4 cv = *(const float4*)&c_lds[j * KRANK + TT * RR + i];
            acc[j] = fmaf(a0, cv.x, fmaf(a1, cv.y, fmaf(a2, cv.z, fmaf(a3, cv.w, acc[j]))));
        }
    }

    #pragma unroll
    for (int j = 0; j < 8; ++j) {
        const int row = rowbase + j;
        Wc[row * DD + d] = (bf16)(qkv_w[row * DD + d] + acc[j]);
    }
}

// ----------------------------------------------------------------- gemm ----
// C[TOK,NOUT] = x[TOK,DD](f32, cast inline) @ Wc[NOUT,DD]^T + bias.
// R13: exact R9 structure (best measured: 128x192 tile, BK=64, 4 waves 2x2,
// single 40KB buffer, 3 blocks/CU, grid 768 = one full round, full-drain
// barriers — 7 structural variants R6-R12 proved sync/traffic/step-count
// all neutral, so keep the simplest best) with ONE change: A is staged
// from x (f32) via reg-staging (2x float4 load -> cvt -> ds_write_b128
// into the byte-identical swizzled layout gl_lds produced). This fuses
// prep's cast pass into the GEMM. x f32 re-reads across the 12 n-blocks
// are L2-hits (3MB per-XCD panel slice < 4MB L2) -> HBM pays x once.
// Staging order per K-step: issue 8 A f32 loads -> issue 6 B gl_lds
// (hides A latency) -> cvt+ds_write A (compiler inserts the vmcnt wait
// for the A loads; B's gl_lds drain at the barrier as before).
__global__ __launch_bounds__(256, 3) void gemm_kernel(
    const float* __restrict__ X, const bf16* __restrict__ B,
    const float* __restrict__ bias, float* __restrict__ C)
{
    __shared__ __align__(16) char smem[40960];  // A 128x64 bf16 (16KB) + B 192x64 bf16 (24KB)
    bf16* const lds_a = (bf16*)smem;
    bf16* const lds_b = (bf16*)(smem + 16384);

    const int tid  = threadIdx.x;
    const int lane = tid & 63;
    const int wave = tid >> 6;

    // XCD swizzle: 768 blocks = 8 XCD x (8 m-tiles x 12 n-tiles)
    const int flat  = blockIdx.x;
    const int xcd   = flat & 7;
    const int local = flat >> 3;           // 0..95
    const int mb    = xcd * 8 + (local & 7);   // 0..63
    const int nb    = local >> 3;              // 0..11
    const int m0 = mb * 128;
    const int n0 = nb * 192;

    // 4 waves: 2x2, each computes 64x96 (4x6 tiles of 16x16)
    const int wm = (wave >> 1) * 64;
    const int wn = (wave & 1) * 96;

    // staging geometry: lane l -> 16B slot l within a 1KB chunk (8 rows x
    // 64 bf16). logical row = l>>3, logical 16B chunk = (l&7)^(l>>3) (XOR
    // swizzle, R6/R9-verified 0 conflicts). Same mapping for reg-staged A.
    const int srow = lane >> 3;                    // 0..7
    const int scol = ((lane & 7) ^ srow) * 8;      // swizzled col (elem units)

    floatx4 acc[4][6];
    #pragma unroll
    for (int i = 0; i < 4; ++i)
        #pragma unroll
        for (int j = 0; j < 6; ++j)
            acc[i][j] = (floatx4){0.f, 0.f, 0.f, 0.f};

    const float* const gAf = X + (m0 + srow) * DD + scol;   // f32 source
    const bf16*  const gB  = B + (n0 + srow) * DD + scol;   // bf16 source

    for (int kt = 0; kt < DD / 64; ++kt) {
        const int k0 = kt * 64;

        // 1) issue A f32 loads: 4 chunks/wave x 2 float4 (row c*8+srow,
        //    cols scol..scol+7 — identical bytes gl_lds would have fetched)
        float4 av0[4], av1[4];
        #pragma unroll
        for (int i = 0; i < 4; ++i) {
            const int c = i * 4 + wave;            // A chunk 0..15
            const float* p = gAf + c * 8 * DD + k0;
            av0[i] = *(const float4*)p;
            av1[i] = *(const float4*)(p + 4);
        }
        // 2) issue B gl_lds (async, 6 chunks/wave) — hides A load latency
        #pragma unroll
        for (int i = 0; i < 6; ++i) {
            const int j = i * 4 + wave;            // 0..23
            gl_lds16(gB + j * 8 * DD + k0, &lds_b[j * 512]);
        }
        // 3) cvt + ds_write A into the same swizzled slots (lane*16B)
        #pragma unroll
        for (int i = 0; i < 4; ++i) {
            const int c = i * 4 + wave;
            bf16x8 o = { (bf16)av0[i].x, (bf16)av0[i].y, (bf16)av0[i].z, (bf16)av0[i].w,
                         (bf16)av1[i].x, (bf16)av1[i].y, (bf16)av1[i].z, (bf16)av1[i].w };
            *(bf16x8*)&lds_a[c * 512 + lane * 8] = o;
        }
        __syncthreads();   // drains gl_lds (vmcnt) + lgkm — tiles visible

        #pragma unroll
        for (int ks = 0; ks < 2; ++ks) {
            const int c_log = ks * 4 + (lane >> 4); // 16B chunk index 0..7
            bf16x8 af[4];
            #pragma unroll
            for (int mt = 0; mt < 4; ++mt) {
                const int r = wm + mt * 16 + (lane & 15);
                af[mt] = *(const bf16x8*)&lds_a[r * 64 + ((c_log ^ (r & 7)) * 8)];
            }
            #pragma unroll
            for (int nt = 0; nt < 6; ++nt) {
                const int r = wn + nt * 16 + (lane & 15);
                const bf16x8 bfr = *(const bf16x8*)&lds_b[r * 64 + ((c_log ^ (r & 7)) * 8)];
                #pragma unroll
                for (int mt = 0; mt < 4; ++mt)
                    acc[mt][nt] = __builtin_amdgcn_mfma_f32_16x16x32_bf16(
                        af[mt], bfr, acc[mt][nt], 0, 0, 0);
            }
        }
        if (kt != DD / 64 - 1) __syncthreads();   // frees LDS for next tile
    }

    // epilogue: direct stores. C/D layout col=lane&15, row=(lane>>4)*4+reg
    const int cr = (lane >> 4) * 4;
    const int cc = lane & 15;
    #pragma unroll
    for (int nt = 0; nt < 6; ++nt) {
        const int gn = n0 + wn + nt * 16 + cc;
        const float bv = bias[gn];
        #pragma unroll
        for (int mt = 0; mt < 4; ++mt) {
            const int gmb = m0 + wm + mt * 16 + cr;
            #pragma unroll
            for (int r = 0; r < 4; ++r)
                C[(gmb + r) * NOUT + gn] = acc[mt][nt][r] + bv;
        }
    }
}

// --------------------------------------------------------------- launch ----
extern "C" void kernel_launch(void* const* d_in, const int* in_sizes, int n_in,
                              void* d_out, int out_size, void* d_ws, size_t ws_size,
                              hipStream_t stream)
{
    const float* x           = (const float*)d_in[0];
    const float* qkv_w       = (const float*)d_in[1];
    const float* qkv_b       = (const float*)d_in[2];
    const float* la_q        = (const float*)d_in[3];
    const float* lb_q        = (const float*)d_in[4];
    const float* la_v        = (const float*)d_in[5];
    const float* lb_v        = (const float*)d_in[6];
    const float* A_q         = (const float*)d_in[7];
    const float* B_q         = (const float*)d_in[8];
    const float* A_v         = (const float*)d_in[9];
    const float* B_v         = (const float*)d_in[10];
    const float* gate_logits = (const float*)d_in[11];
    const float* alpha       = (const float*)d_in[12];
    float* out = (float*)d_out;

    char* ws = (char*)d_ws;
    bf16*  Wc     = (bf16*)ws;                    //  3,538,944 B
    float* norms  = (float*)(ws + 3538944);       // 32 floats

    prep_kernel<<<32, 256, 0, stream>>>(A_q, B_q, A_v, B_v, norms);
    fold_kernel<<<dim3(3, 288), 256, 0, stream>>>(qkv_w,
                                                  A_q, la_q, B_q, lb_q,
                                                  A_v, la_v, B_v, lb_v,
                                                  gate_logits, alpha, norms, Wc);
    gemm_kernel<<<768, 256, 0, stream>>>(x, Wc, qkv_b, out);
}

// Round 8
// 177.033 us; speedup vs baseline: 1.0173x; 1.0173x over previous
//
#include <hip/hip_runtime.h>

// Problem dims (ViT-Base LoRA-MoE qkv)
#define TOK 8192      // B*S = 32*256
#define DD  768       // in features
#define NOUT 2304     // 3*D
#define TT  8         // saved tasks
#define RR  16        // LoRA rank
#define KRANK 144     // T*R + R (per branch folded rank)

typedef __bf16 bf16;
typedef __bf16 bf16x4 __attribute__((ext_vector_type(4)));
typedef __bf16 bf16x8 __attribute__((ext_vector_type(8)));
typedef float  floatx4 __attribute__((ext_vector_type(4)));

__device__ __forceinline__ void gl_lds16(const void* g, void* l) {
    __builtin_amdgcn_global_load_lds((const __attribute__((address_space(1))) void*)g,
                                     (__attribute__((address_space(3))) void*)l, 16, 0, 0);
}

// ----------------------------------------------------------------- prep ----
// blocks 0..31: Frobenius norms of {A_q,B_q,A_v,B_v}[task]  (b>>3 selects
// tensor, b&7 selects task). blocks 32..3103: fp32->bf16 cast of x,
// 8 elems/thread (bf16x8 16B stores).  (R9-verified; R13's cast-fusion
// into gemm measured WORSE — reg-staging chain cost > saved pass.)
__global__ __launch_bounds__(256) void prep_kernel(
    const float* __restrict__ A_q, const float* __restrict__ B_q,
    const float* __restrict__ A_v, const float* __restrict__ B_v,
    const float* __restrict__ x, bf16* __restrict__ xb,
    float* __restrict__ norms)
{
    __shared__ float ws4[4];
    const int b = blockIdx.x;
    if (b < 32) {
        const float* base;
        switch (b >> 3) {
            case 0: base = A_q; break;
            case 1: base = B_q; break;
            case 2: base = A_v; break;
            default: base = B_v; break;
        }
        base += (b & 7) * (RR * DD);
        float s = 0.f;
        for (int i = threadIdx.x; i < RR * DD; i += 256) {
            float v = base[i];
            s = fmaf(v, v, s);
        }
        #pragma unroll
        for (int off = 32; off > 0; off >>= 1) s += __shfl_down(s, off);
        if ((threadIdx.x & 63) == 0) ws4[threadIdx.x >> 6] = s;
        __syncthreads();
        if (threadIdx.x == 0)
            norms[b] = sqrtf(ws4[0] + ws4[1] + ws4[2] + ws4[3]);
    } else {
        const int idx = ((b - 32) * 256 + threadIdx.x) * 8;
        const float4 v0 = *(const float4*)(x + idx);
        const float4 v1 = *(const float4*)(x + idx + 4);
        bf16x8 o = { (bf16)v0.x, (bf16)v0.y, (bf16)v0.z, (bf16)v0.w,
                     (bf16)v1.x, (bf16)v1.y, (bf16)v1.z, (bf16)v1.w };
        *(bf16x8*)(xb + idx) = o;
    }
}

// ----------------------------------------------------------------- fold ----
// Wc[row] = bf16(qkv_w[row] + sum_i c[row][i] * Acat[i][:]) for q/v thirds;
// plain bf16 cast for the k third. grid = (3, 288).  (unchanged, verified)
__global__ __launch_bounds__(256) void fold_kernel(
    const float* __restrict__ qkv_w,
    const float* __restrict__ A_q, const float* __restrict__ la_q,
    const float* __restrict__ B_q, const float* __restrict__ lb_q,
    const float* __restrict__ A_v, const float* __restrict__ la_v,
    const float* __restrict__ B_v, const float* __restrict__ lb_v,
    const float* __restrict__ gate_logits, const float* __restrict__ alpha,
    const float* __restrict__ norms, bf16* __restrict__ Wc)
{
    const int tid = threadIdx.x;
    const int d = blockIdx.x * 256 + tid;
    const int gy = blockIdx.y;

    if (gy >= 96 && gy < 192) {           // k third: pure cast
        const int rowbase = DD + (gy - 96) * 8;
        #pragma unroll
        for (int j = 0; j < 8; ++j) {
            const int row = rowbase + j;
            Wc[row * DD + d] = (bf16)qkv_w[row * DD + d];
        }
        return;
    }

    __shared__ float c_lds[8 * KRANK];
    __shared__ float sc_sh[TT];
    __shared__ float acur_sh;

    const bool is_v = (gy >= 192);
    const int e0 = (is_v ? gy - 192 : gy) * 8;
    const float* Astack = is_v ? A_v : A_q;
    const float* la     = is_v ? la_v : la_q;
    const float* Bmat   = is_v ? B_v : B_q;
    const float* lb     = is_v ? lb_v : lb_q;
    const float* nA     = norms + (is_v ? 16 : 0);
    const float* nB     = norms + (is_v ? 24 : 8);
    const int rowbase   = (is_v ? 2 * DD : 0) + e0;

    if (tid == 0) {
        float mx = gate_logits[0];
        for (int t = 1; t < TT; ++t) mx = fmaxf(mx, gate_logits[t]);
        float e[TT], s = 0.f;
        for (int t = 0; t < TT; ++t) { e[t] = __expf(gate_logits[t] - mx); s += e[t]; }
        for (int t = 0; t < TT; ++t) sc_sh[t] = (e[t] / s) / (nA[t] * nB[t]);
        acur_sh = alpha[TT];
    }
    __syncthreads();

    for (int idx = tid; idx < 8 * KRANK; idx += 256) {
        const int j = idx / KRANK, i = idx - j * KRANK;
        const int e = e0 + j;
        float v;
        if (i < TT * RR) {
            const int t = i >> 4, r = i & 15;
            v = sc_sh[t] * Bmat[(t * DD + e) * RR + r];
        } else {
            v = acur_sh * lb[e * RR + (i - TT * RR)];
        }
        c_lds[j * KRANK + i] = v;
    }
    __syncthreads();

    float acc[8] = {0.f, 0.f, 0.f, 0.f, 0.f, 0.f, 0.f, 0.f};

    for (int i = 0; i < TT * RR; i += 4) {
        const float a0 = Astack[(i + 0) * DD + d];
        const float a1 = Astack[(i + 1) * DD + d];
        const float a2 = Astack[(i + 2) * DD + d];
        const float a3 = Astack[(i + 3) * DD + d];
        #pragma unroll
        for (int j = 0; j < 8; ++j) {
            const float4 cv = *(const float4*)&c_lds[j * KRANK + i];
            acc[j] = fmaf(a0, cv.x, fmaf(a1, cv.y, fmaf(a2, cv.z, fmaf(a3, cv.w, acc[j]))));
        }
    }
    #pragma unroll
    for (int i = 0; i < RR; i += 4) {
        const float a0 = la[(i + 0) * DD + d];
        const float a1 = la[(i + 1) * DD + d];
        const float a2 = la[(i + 2) * DD + d];
        const float a3 = la[(i + 3) * DD + d];
        #pragma unroll
        for (int j = 0; j < 8; ++j) {
            const float4 cv = *(const float4*)&c_lds[j * KRANK + TT * RR + i];
            acc[j] = fmaf(a0, cv.x, fmaf(a1, cv.y, fmaf(a2, cv.z, fmaf(a3, cv.w, acc[j]))));
        }
    }

    #pragma unroll
    for (int j = 0; j < 8; ++j) {
        const int row = rowbase + j;
        Wc[row * DD + d] = (bf16)(qkv_w[row * DD + d] + acc[j]);
    }
}

// ----------------------------------------------------------------- gemm ----
// C[TOK,NOUT] = Xbf[TOK,DD] @ Wc[NOUT,DD]^T + bias.
// R14: exact revert to R9 — the best measured configuration (171.25us
// total). 128x192 tile, BK=64, 4 waves 2x2 (wave 64x96, 4x6 acc), single
// 40KB LDS buffer -> 3 blocks/CU, grid 768 = one full residency round,
// full-drain __syncthreads() loop, R6-proven chunk staging + XOR swizzle
// (0 conflicts). Eight structural variants (R7 counted-vmcnt, R8 BK32-dbuf,
// R10 triple-buf+setprio, R11 32x32-MFMA, R12 BK128, R13 cast-fusion) all
// measured neutral-to-worse: this thin-K shape sits at its structure-class
// floor (~650 TF) and the simplest best config wins. Only tweak kept from
// R12: skip the final-iteration barrier (proven safe, passed).
__global__ __launch_bounds__(256, 3) void gemm_kernel(
    const bf16* __restrict__ A, const bf16* __restrict__ B,
    const float* __restrict__ bias, float* __restrict__ C)
{
    __shared__ __align__(16) char smem[40960];  // A 128x64 bf16 (16KB) + B 192x64 bf16 (24KB)
    bf16* const lds_a = (bf16*)smem;
    bf16* const lds_b = (bf16*)(smem + 16384);

    const int tid  = threadIdx.x;
    const int lane = tid & 63;
    const int wave = tid >> 6;

    // XCD swizzle: 768 blocks = 8 XCD x (8 m-tiles x 12 n-tiles)
    const int flat  = blockIdx.x;
    const int xcd   = flat & 7;
    const int local = flat >> 3;           // 0..95
    const int mb    = xcd * 8 + (local & 7);   // 0..63
    const int nb    = local >> 3;              // 0..11
    const int m0 = mb * 128;
    const int n0 = nb * 192;

    // 4 waves: 2x2, each computes 64x96 (4x6 tiles of 16x16)
    const int wm = (wave >> 1) * 64;
    const int wn = (wave & 1) * 96;

    // staging: lane l -> slot l (16B) within a 1KB chunk (8 rows x 64 bf16).
    // logical row = l>>3, logical 16B chunk = (l&7) ^ (l>>3)  (XOR swizzle,
    // R6/R9-verified: 0 bank conflicts).
    const int srow = lane >> 3;                    // 0..7
    const int scol = ((lane & 7) ^ srow) * 8;      // swizzled col (bf16 units)

    floatx4 acc[4][6];
    #pragma unroll
    for (int i = 0; i < 4; ++i)
        #pragma unroll
        for (int j = 0; j < 6; ++j)
            acc[i][j] = (floatx4){0.f, 0.f, 0.f, 0.f};

    const bf16* const gA = A + (m0 + srow) * DD + scol;
    const bf16* const gB = B + (n0 + srow) * DD + scol;

    for (int kt = 0; kt < DD / 64; ++kt) {
        const int k0 = kt * 64;
        // stage A: 16 chunks of 8 rows; B: 24 chunks. round-robin by wave
        // -> 10 chunks per wave.
        #pragma unroll
        for (int i = 0; i < 4; ++i) {
            const int j = i * 4 + wave;            // 0..15
            gl_lds16(gA + j * 8 * DD + k0, &lds_a[j * 512]);
        }
        #pragma unroll
        for (int i = 0; i < 6; ++i) {
            const int j = i * 4 + wave;            // 0..23
            gl_lds16(gB + j * 8 * DD + k0, &lds_b[j * 512]);
        }
        __syncthreads();   // drains gl_lds (vmcnt) — tiles visible to all

        #pragma unroll
        for (int ks = 0; ks < 2; ++ks) {
            const int c_log = ks * 4 + (lane >> 4); // 16B chunk index 0..7
            bf16x8 af[4];
            #pragma unroll
            for (int mt = 0; mt < 4; ++mt) {
                const int r = wm + mt * 16 + (lane & 15);
                af[mt] = *(const bf16x8*)&lds_a[r * 64 + ((c_log ^ (r & 7)) * 8)];
            }
            #pragma unroll
            for (int nt = 0; nt < 6; ++nt) {
                const int r = wn + nt * 16 + (lane & 15);
                const bf16x8 bfr = *(const bf16x8*)&lds_b[r * 64 + ((c_log ^ (r & 7)) * 8)];
                #pragma unroll
                for (int mt = 0; mt < 4; ++mt)
                    acc[mt][nt] = __builtin_amdgcn_mfma_f32_16x16x32_bf16(
                        af[mt], bfr, acc[mt][nt], 0, 0, 0);
            }
        }
        if (kt != DD / 64 - 1) __syncthreads();   // frees LDS for next tile
    }

    // epilogue: direct stores. C/D layout col=lane&15, row=(lane>>4)*4+reg
    const int cr = (lane >> 4) * 4;
    const int cc = lane & 15;
    #pragma unroll
    for (int nt = 0; nt < 6; ++nt) {
        const int gn = n0 + wn + nt * 16 + cc;
        const float bv = bias[gn];
        #pragma unroll
        for (int mt = 0; mt < 4; ++mt) {
            const int gmb = m0 + wm + mt * 16 + cr;
            #pragma unroll
            for (int r = 0; r < 4; ++r)
                C[(gmb + r) * NOUT + gn] = acc[mt][nt][r] + bv;
        }
    }
}

// --------------------------------------------------------------- launch ----
extern "C" void kernel_launch(void* const* d_in, const int* in_sizes, int n_in,
                              void* d_out, int out_size, void* d_ws, size_t ws_size,
                              hipStream_t stream)
{
    const float* x           = (const float*)d_in[0];
    const float* qkv_w       = (const float*)d_in[1];
    const float* qkv_b       = (const float*)d_in[2];
    const float* la_q        = (const float*)d_in[3];
    const float* lb_q        = (const float*)d_in[4];
    const float* la_v        = (const float*)d_in[5];
    const float* lb_v        = (const float*)d_in[6];
    const float* A_q         = (const float*)d_in[7];
    const float* B_q         = (const float*)d_in[8];
    const float* A_v         = (const float*)d_in[9];
    const float* B_v         = (const float*)d_in[10];
    const float* gate_logits = (const float*)d_in[11];
    const float* alpha       = (const float*)d_in[12];
    float* out = (float*)d_out;

    char* ws = (char*)d_ws;
    bf16*  Xbf    = (bf16*)ws;                                  // 12,582,912 B
    bf16*  Wc     = (bf16*)(ws + 12582912);                     //  3,538,944 B
    float* norms  = (float*)(ws + 12582912 + 3538944);          // 32 floats

    prep_kernel<<<32 + TOK * DD / 2048, 256, 0, stream>>>(A_q, B_q, A_v, B_v,
                                                          x, Xbf, norms);
    fold_kernel<<<dim3(3, 288), 256, 0, stream>>>(qkv_w,
                                                  A_q, la_q, B_q, lb_q,
                                                  A_v, la_v, B_v, lb_v,
                                                  gate_logits, alpha, norms, Wc);
    gemm_kernel<<<768, 256, 0, stream>>>(Xbf, Wc, qkv_b, out);
}